// Round 14
// baseline (193.484 us; speedup 1.0000x reference)
//
#include <hip/hip_runtime.h>
#include <hip/hip_bf16.h>
#include <stdint.h>

#define N_NODES   50000
#define N_EDGES   800000
#define F_IN      64
#define HID       128
#define N_CLASSES 10
#define NUM_GRAPHS 512

// bucket-sort CSR build parameters
#define NBUCK 128      // buckets over dst
#define BW    391      // bucket width: 391*128 = 50048 >= N
#define S1B   400      // blocks in bucket hist/scatter
#define CHUNK 2000     // edges per block (400*2000 = 800000)
#define MCNT  (NBUCK * S1B)   // 51200 counters
#define SCB   (MCNT / 256)    // 200 scanA blocks
#define PREPB 3125     // blocks for prep range (N*F_IN/4/256)
#define MAXB  8192     // LDS staging capacity per bucket (mean 6250)

typedef unsigned int uint32;
typedef __attribute__((ext_vector_type(8))) short bf16x8;
typedef __attribute__((ext_vector_type(4))) float f32x4;

// ---------------- bf16 helpers (storage bf16, math fp32) ----------------
__device__ __forceinline__ float bl(uint32 w) { return __uint_as_float(w << 16); }
__device__ __forceinline__ float bh(uint32 w) { return __uint_as_float(w & 0xffff0000u); }
__device__ __forceinline__ float b1f(unsigned short h) { return __uint_as_float((uint32)h << 16); }
__device__ __forceinline__ uint32 packbf(float a, float b) {   // RNE, (a=low, b=high)
    uint32 ua = __float_as_uint(a), ub = __float_as_uint(b);
    ua = (ua + 0x7fffu + ((ua >> 16) & 1u)) >> 16;
    ub = (ub + 0x7fffu + ((ub >> 16) & 1u)) >> 16;
    return ua | (ub << 16);
}
__device__ __forceinline__ unsigned short packbf1(float a) {
    uint32 ua = __float_as_uint(a);
    return (unsigned short)((ua + 0x7fffu + ((ua >> 16) & 1u)) >> 16);
}

// physical column permutation for u8 activation rows: lane-contiguous stores
// phys(c) = (c&15)*8 + (c>>4)

// ---------------------------------------------------------------- prep + bucket hist (fused, disjoint block ranges)
__global__ __launch_bounds__(256) void prep_hist_kernel(const float4* __restrict__ x, uint2* __restrict__ xb,
                                                        const float* __restrict__ W0, unsigned short* __restrict__ W0t,
                                                        const float* __restrict__ W1, unsigned short* __restrict__ W1t,
                                                        const float* __restrict__ W2, unsigned short* __restrict__ W2t,
                                                        float* __restrict__ g,
                                                        const int* __restrict__ dst, int* __restrict__ bcnt, int E) {
    __shared__ int cnt[NBUCK];
    int blk = blockIdx.x;
    int t = threadIdx.x;
    if (blk < PREPB) {
        int i = blk * 256 + t;
        if (i < N_NODES * F_IN / 4) {
            float4 v = x[i];
            xb[i] = make_uint2(packbf(v.x, v.y), packbf(v.z, v.w));
        }
        if (i < NUM_GRAPHS * HID) g[i] = 0.f;
        if (i < 64 * 128) {
            int k = i >> 7, j = i & 127;
            W0t[j * (64 + 8) + k] = packbf1(W0[i]);   // natural rows (agg0 is bf16 natural)
        }
        int i2 = i - 64 * 128;
        if (i2 >= 0 && i2 < 128 * 128) {
            int k = i2 >> 7, j = i2 & 127;
            int kp = (k & 15) * 8 + (k >> 4);          // permuted rows (agg1/agg2 are physical order)
            W1t[j * (128 + 8) + kp] = packbf1(W1[i2]);
            W2t[j * (128 + 8) + kp] = packbf1(W2[i2]);
        }
    } else {
        int b2 = blk - PREPB;                  // 0..S1B-1
        if (t < NBUCK) cnt[t] = 0;
        __syncthreads();
        int base = b2 * CHUNK;
        for (int i = t; i < CHUNK; i += 256) {
            int e = base + i;
            if (e < E) atomicAdd(&cnt[(uint32)dst[e] / BW], 1);
        }
        __syncthreads();
        if (t < NBUCK) bcnt[t * S1B + b2] = cnt[t];   // bucket-major layout
    }
}

// ------------------------------------------------- scanA (per-256 inclusive + raw block sums)
__global__ __launch_bounds__(256) void scanA_kernel(const int* __restrict__ in,
                                                    int* __restrict__ incl,
                                                    int* __restrict__ bsum_raw, int M) {
    __shared__ int s[256];
    int t = threadIdx.x;
    int i = blockIdx.x * 256 + t;
    int v = (i < M) ? in[i] : 0;
    s[t] = v;
    __syncthreads();
    #pragma unroll
    for (int d = 1; d < 256; d <<= 1) {
        int a = (t >= d) ? s[t - d] : 0;
        __syncthreads();
        s[t] += a;
        __syncthreads();
    }
    if (i < M) incl[i] = s[t];
    if (t == 255) bsum_raw[blockIdx.x] = s[255];
}

// local exclusive scan of the 200 raw block sums (device helper)
__device__ __forceinline__ void local_top_scan(const int* __restrict__ bsum_raw, int* exs, int t) {
    int bv = (t < SCB) ? bsum_raw[t] : 0;
    exs[t] = bv;
    __syncthreads();
    #pragma unroll
    for (int d = 1; d < 256; d <<= 1) {
        int a = (t >= d) ? exs[t - d] : 0;
        __syncthreads();
        exs[t] += a;
        __syncthreads();
    }
    int iv = exs[t];
    __syncthreads();
    exs[t] = iv - bv;      // exclusive
    __syncthreads();
}

// S2: scatter edges into bucket-grouped ebuf (LDS cursors; 4B packed src|dst<<16)
__global__ __launch_bounds__(256) void bscatter_kernel(const int* __restrict__ src,
                                                       const int* __restrict__ dst,
                                                       const int* __restrict__ incl,
                                                       const int* __restrict__ bsum_raw,
                                                       uint32* __restrict__ ebuf, int E) {
    __shared__ int exs[256];
    __shared__ int cnt[NBUCK];
    __shared__ int cur[NBUCK];
    int t = threadIdx.x, blk = blockIdx.x;

    local_top_scan(bsum_raw, exs, t);

    if (t < NBUCK) cnt[t] = 0;
    __syncthreads();
    int base = blk * CHUNK;
    for (int i = t; i < CHUNK; i += 256) {
        int e = base + i;
        if (e < E) atomicAdd(&cnt[(uint32)dst[e] / BW], 1);
    }
    __syncthreads();
    if (t < NBUCK) {
        int idx = t * S1B + blk;
        cur[t] = exs[idx >> 8] + incl[idx] - cnt[t];   // global exclusive base
    }
    __syncthreads();
    for (int i = t; i < CHUNK; i += 256) {
        int e = base + i;
        if (e < E) {
            int d = dst[e];
            int slot = atomicAdd(&cur[(uint32)d / BW], 1);
            ebuf[slot] = (uint32)src[e] | ((uint32)d << 16);
        }
    }
}

// S3: per-bucket CSR finalize
__global__ __launch_bounds__(256) void bfinal_kernel(const uint32* __restrict__ ebuf,
                                                     const int* __restrict__ bcnt,
                                                     const int* __restrict__ incl,
                                                     const int* __restrict__ bsum_raw,
                                                     int2* __restrict__ rowse,
                                                     float* __restrict__ dinv,
                                                     uint32* __restrict__ meta, int E, int N) {
    __shared__ int exs[256];
    __shared__ int cnt[392];
    __shared__ int startv[400];
    __shared__ int segt[16];
    __shared__ uint32 smeta[MAXB];
    int t = threadIdx.x, b = blockIdx.x;

    local_top_scan(bsum_raw, exs, t);

    int bs, be;
    {
        int idx = b * S1B;
        bs = exs[idx >> 8] + incl[idx] - bcnt[idx];
        if (b + 1 >= NBUCK) be = E;
        else {
            int idx1 = (b + 1) * S1B;
            be = exs[idx1 >> 8] + incl[idx1] - bcnt[idx1];
        }
    }
    int sz = be - bs;

    for (int i = t; i < 392; i += 256) cnt[i] = 0;
    __syncthreads();
    for (int i = bs + t; i < be; i += 256) {
        uint32 d = ebuf[i] >> 16;
        atomicAdd(&cnt[d - b * BW], 1);
    }
    __syncthreads();

    if (t < 16) {
        int run = 0;
        #pragma unroll
        for (int k = 0; k < 25; k++) {
            int idx = t * 25 + k;
            int c = (idx < 391) ? cnt[idx] : 0;
            startv[idx] = run;
            run += c;
        }
        segt[t] = run;
    }
    __syncthreads();
    if (t == 0) {
        int run = 0;
        #pragma unroll
        for (int j = 0; j < 16; j++) { int s = segt[j]; segt[j] = run; run += s; }
    }
    __syncthreads();
    for (int l = t; l < 391; l += 256) startv[l] += segt[l / 25];
    __syncthreads();

    int locN = N - b * BW; if (locN > BW) locN = BW;
    for (int l = t; l < locN; l += 256) {
        int gn = b * BW + l;
        int st = bs + startv[l];
        rowse[gn] = make_int2(st, st + cnt[l]);
        dinv[gn] = rsqrtf((float)(cnt[l] + 1));
    }
    __syncthreads();

    if (sz <= MAXB) {
        for (int i = bs + t; i < be; i += 256) {
            uint32 v = ebuf[i];
            int slot = atomicAdd(&startv[(v >> 16) - b * BW], 1);
            smeta[slot] = v;
        }
        __syncthreads();
        for (int i = t; i < sz; i += 256) meta[bs + i] = smeta[i];
    } else {
        for (int i = bs + t; i < be; i += 256) {
            uint32 v = ebuf[i];
            int slot = atomicAdd(&startv[(v >> 16) - b * BW], 1);
            meta[bs + slot] = v;
        }
    }
}

// ---------------------------------------------------------------- SpMM 64-wide bf16 + norm fill (4-deep)
__global__ __launch_bounds__(256) void spmm64_kernel(const int2* __restrict__ rowse,
                                                     uint32* __restrict__ meta,
                                                     const float* __restrict__ dinv,
                                                     const unsigned short* __restrict__ Hin,
                                                     unsigned short* __restrict__ Hout, int N) {
    int wave = threadIdx.x >> 6;
    int lane = threadIdx.x & 63;
    int node = blockIdx.x * 4 + wave;
    if (node >= N) return;
    int oct = lane >> 3;
    int sub = lane & 7;

    const uint4* Hv = (const uint4*)Hin;     // row = 8 chunks of 8 bf16
    float di = dinv[node];
    float sn = di * di;

    float acc[8];
    if (oct == 0) {
        uint4 s = Hv[(size_t)node * 8 + sub];
        acc[0] = sn * bl(s.x); acc[1] = sn * bh(s.x);
        acc[2] = sn * bl(s.y); acc[3] = sn * bh(s.y);
        acc[4] = sn * bl(s.z); acc[5] = sn * bh(s.z);
        acc[6] = sn * bl(s.w); acc[7] = sn * bh(s.w);
    } else {
        #pragma unroll
        for (int v = 0; v < 8; v++) acc[v] = 0.f;
    }

    int2 se = rowse[node];
    int e0 = se.x, e1 = se.y;
    for (int e = e0; e < e1; e += 32) {
        int i0 = e + oct;
        int i1 = e + 8 + oct;
        int i2 = e + 16 + oct;
        int i3 = e + 24 + oct;
        bool v0 = i0 < e1, v1 = i1 < e1, v2 = i2 < e1, v3 = i3 < e1;
        uint32 m0 = v0 ? meta[i0] : 0u;
        uint32 m1 = v1 ? meta[i1] : 0u;
        uint32 m2 = v2 ? meta[i2] : 0u;
        uint32 m3 = v3 ? meta[i3] : 0u;
        uint32 s0 = m0 & 0xffffu, s1 = m1 & 0xffffu;
        uint32 s2 = m2 & 0xffffu, s3 = m3 & 0xffffu;
        float n0 = v0 ? di * dinv[s0] : 0.f;
        float n1 = v1 ? di * dinv[s1] : 0.f;
        float n2 = v2 ? di * dinv[s2] : 0.f;
        float n3 = v3 ? di * dinv[s3] : 0.f;
        if (sub == 0) {   // one lane per edge writes the normed meta back
            if (v0) meta[i0] = s0 | ((uint32)packbf1(n0) << 16);
            if (v1) meta[i1] = s1 | ((uint32)packbf1(n1) << 16);
            if (v2) meta[i2] = s2 | ((uint32)packbf1(n2) << 16);
            if (v3) meta[i3] = s3 | ((uint32)packbf1(n3) << 16);
        }
        uint4 r0 = Hv[(size_t)s0 * 8 + sub];
        uint4 r1 = Hv[(size_t)s1 * 8 + sub];
        uint4 r2 = Hv[(size_t)s2 * 8 + sub];
        uint4 r3 = Hv[(size_t)s3 * 8 + sub];
        acc[0] = fmaf(n0, bl(r0.x), acc[0]); acc[1] = fmaf(n0, bh(r0.x), acc[1]);
        acc[2] = fmaf(n0, bl(r0.y), acc[2]); acc[3] = fmaf(n0, bh(r0.y), acc[3]);
        acc[4] = fmaf(n0, bl(r0.z), acc[4]); acc[5] = fmaf(n0, bh(r0.z), acc[5]);
        acc[6] = fmaf(n0, bl(r0.w), acc[6]); acc[7] = fmaf(n0, bh(r0.w), acc[7]);
        acc[0] = fmaf(n1, bl(r1.x), acc[0]); acc[1] = fmaf(n1, bh(r1.x), acc[1]);
        acc[2] = fmaf(n1, bl(r1.y), acc[2]); acc[3] = fmaf(n1, bh(r1.y), acc[3]);
        acc[4] = fmaf(n1, bl(r1.z), acc[4]); acc[5] = fmaf(n1, bh(r1.z), acc[5]);
        acc[6] = fmaf(n1, bl(r1.w), acc[6]); acc[7] = fmaf(n1, bh(r1.w), acc[7]);
        acc[0] = fmaf(n2, bl(r2.x), acc[0]); acc[1] = fmaf(n2, bh(r2.x), acc[1]);
        acc[2] = fmaf(n2, bl(r2.y), acc[2]); acc[3] = fmaf(n2, bh(r2.y), acc[3]);
        acc[4] = fmaf(n2, bl(r2.z), acc[4]); acc[5] = fmaf(n2, bh(r2.z), acc[5]);
        acc[6] = fmaf(n2, bl(r2.w), acc[6]); acc[7] = fmaf(n2, bh(r2.w), acc[7]);
        acc[0] = fmaf(n3, bl(r3.x), acc[0]); acc[1] = fmaf(n3, bh(r3.x), acc[1]);
        acc[2] = fmaf(n3, bl(r3.y), acc[2]); acc[3] = fmaf(n3, bh(r3.y), acc[3]);
        acc[4] = fmaf(n3, bl(r3.z), acc[4]); acc[5] = fmaf(n3, bh(r3.z), acc[5]);
        acc[6] = fmaf(n3, bl(r3.w), acc[6]); acc[7] = fmaf(n3, bh(r3.w), acc[7]);
    }

    #pragma unroll
    for (int v = 0; v < 8; v++) {
        acc[v] += __shfl_xor(acc[v], 8);
        acc[v] += __shfl_xor(acc[v], 16);
        acc[v] += __shfl_xor(acc[v], 32);
    }

    if (oct == 0) {
        uint4 o;
        o.x = packbf(acc[0], acc[1]);
        o.y = packbf(acc[2], acc[3]);
        o.z = packbf(acc[4], acc[5]);
        o.w = packbf(acc[6], acc[7]);
        ((uint4*)Hout)[(size_t)node * 8 + sub] = o;
    }
}

// ---------------------------------------------------------------- SpMM 128-wide over u8-quantized rows (4-deep)
// Hq rows: 128 u8 (physical col order) + per-row f32 scale. Output: bf16 agg rows (physical order).
__device__ __forceinline__ void fma16_u8(uint4 u, float ns, float* acc) {
    #pragma unroll
    for (int w = 0; w < 4; w++) {
        uint32 xv = (&u.x)[w];
        acc[w * 4 + 0] = fmaf(ns, (float)(xv & 255u),         acc[w * 4 + 0]);
        acc[w * 4 + 1] = fmaf(ns, (float)((xv >> 8) & 255u),  acc[w * 4 + 1]);
        acc[w * 4 + 2] = fmaf(ns, (float)((xv >> 16) & 255u), acc[w * 4 + 2]);
        acc[w * 4 + 3] = fmaf(ns, (float)(xv >> 24),          acc[w * 4 + 3]);
    }
}

__global__ __launch_bounds__(256) void spmm128q_kernel(const int2* __restrict__ rowse,
                                                       const uint32* __restrict__ meta,
                                                       const float* __restrict__ dinv,
                                                       const unsigned char* __restrict__ Hq,
                                                       const float* __restrict__ scale,
                                                       unsigned short* __restrict__ Hout, int N) {
    int wave = threadIdx.x >> 6;
    int lane = threadIdx.x & 63;
    int node = blockIdx.x * 4 + wave;
    if (node >= N) return;
    int oct = lane >> 3;     // edge slot 0..7
    int sub = lane & 7;      // 16B chunk 0..7

    const uint4* Hv = (const uint4*)Hq;      // row = 8 uint4 (128 u8)
    float di = dinv[node];
    float sn = di * di;

    float acc[16];
    #pragma unroll
    for (int v = 0; v < 16; v++) acc[v] = 0.f;
    if (oct == 0) {
        uint4 u = Hv[(size_t)node * 8 + sub];
        float ss = sn * scale[node];
        fma16_u8(u, ss, acc);
    }

    int2 se = rowse[node];
    int e0 = se.x, e1 = se.y;
    for (int e = e0; e < e1; e += 32) {
        int i0 = e + oct;
        int i1 = e + 8 + oct;
        int i2 = e + 16 + oct;
        int i3 = e + 24 + oct;
        uint32 m0 = (i0 < e1) ? meta[i0] : 0u;   // norm=0 -> no-op
        uint32 m1 = (i1 < e1) ? meta[i1] : 0u;
        uint32 m2 = (i2 < e1) ? meta[i2] : 0u;
        uint32 m3 = (i3 < e1) ? meta[i3] : 0u;
        uint32 s0 = m0 & 0xffffu, s1 = m1 & 0xffffu;
        uint32 s2 = m2 & 0xffffu, s3 = m3 & 0xffffu;
        float ns0 = bh(m0) * scale[s0];
        float ns1 = bh(m1) * scale[s1];
        float ns2 = bh(m2) * scale[s2];
        float ns3 = bh(m3) * scale[s3];
        uint4 u0 = Hv[(size_t)s0 * 8 + sub];
        uint4 u1 = Hv[(size_t)s1 * 8 + sub];
        uint4 u2 = Hv[(size_t)s2 * 8 + sub];
        uint4 u3 = Hv[(size_t)s3 * 8 + sub];
        fma16_u8(u0, ns0, acc);
        fma16_u8(u1, ns1, acc);
        fma16_u8(u2, ns2, acc);
        fma16_u8(u3, ns3, acc);
    }

    #pragma unroll
    for (int v = 0; v < 16; v++) {
        acc[v] += __shfl_xor(acc[v], 8);
        acc[v] += __shfl_xor(acc[v], 16);
        acc[v] += __shfl_xor(acc[v], 32);
    }

    if (oct == 0) {
        uint32 o[8];
        #pragma unroll
        for (int i = 0; i < 8; i++) o[i] = packbf(acc[2 * i], acc[2 * i + 1]);
        uint4* dst = (uint4*)(Hout + (size_t)node * 128) + sub * 2;
        dst[0] = make_uint4(o[0], o[1], o[2], o[3]);
        dst[1] = make_uint4(o[4], o[5], o[6], o[7]);
    }
}

// ---------------------------------------------------------------- MFMA GEMM (bf16 A/W)
// POOL=false: epilogue quantizes rows to u8 (physical col order) + per-row scale.
// POOL=true : epilogue stages bf16 tile in LDS and does fused global-add-pool.
template <int K, bool POOL>
__global__ __launch_bounds__(256) void gemm_mfma_kernel(const unsigned short* __restrict__ A,
                                                        const unsigned short* __restrict__ Wt,
                                                        const float* __restrict__ bias,
                                                        unsigned char* __restrict__ Hq,
                                                        float* __restrict__ scale,
                                                        const int* __restrict__ batch,
                                                        float* __restrict__ g,
                                                        int N) {
    constexpr int KP = K + 8;
    __shared__ unsigned short Wl[128 * KP];
    __shared__ unsigned short Hl[POOL ? 128 * 128 : 1];

    int t = threadIdx.x;
    constexpr int TOT = 128 * KP * 2 / 16;     // uint4 chunks
    #pragma unroll
    for (int i = 0; i < (TOT + 255) / 256; i++) {
        int idx = i * 256 + t;
        if (idx < TOT) ((uint4*)Wl)[idx] = ((const uint4*)Wt)[idx];
    }
    __syncthreads();

    int wave = t >> 6;
    int lane = t & 63;
    int rowBase = blockIdx.x * 128 + wave * 32;
    int r0 = rowBase + (lane & 15);
    int r1 = r0 + 16;
    if (r0 >= N) r0 = N - 1;                   // clamp (stores predicated)
    if (r1 >= N) r1 = N - 1;
    int kchunk = lane >> 4;                    // 0..3
    int colSub = lane & 15;

    f32x4 acc0[8], acc1[8];
    #pragma unroll
    for (int i = 0; i < 8; i++) { acc0[i] = (f32x4)0.0f; acc1[i] = (f32x4)0.0f; }

    #pragma unroll
    for (int s = 0; s < K / 32; s++) {
        bf16x8 a0 = *(const bf16x8*)(A + (size_t)r0 * K + s * 32 + kchunk * 8);
        bf16x8 a1 = *(const bf16x8*)(A + (size_t)r1 * K + s * 32 + kchunk * 8);
        #pragma unroll
        for (int tl = 0; tl < 8; tl++) {
            bf16x8 b = *(const bf16x8*)(Wl + (tl * 16 + colSub) * KP + s * 32 + kchunk * 8);
            acc0[tl] = __builtin_amdgcn_mfma_f32_16x16x32_bf16(a0, b, acc0[tl], 0, 0, 0);
            acc1[tl] = __builtin_amdgcn_mfma_f32_16x16x32_bf16(a1, b, acc1[tl], 0, 0, 0);
        }
    }

    int rowOff = (lane >> 4) * 4;
    if (!POOL) {
        // quantize each output row to u8 with per-row scale; lane stores 8 contiguous bytes
        auto quant_rows = [&](f32x4 (&ac)[8], int rbase) {
            #pragma unroll
            for (int r = 0; r < 4; r++) {
                int row = rbase + r;
                float v[8];
                float m = 0.f;
                #pragma unroll
                for (int tl = 0; tl < 8; tl++) {
                    float tv = fmaxf(ac[tl][r] + bias[tl * 16 + colSub], 0.f);
                    v[tl] = tv;
                    m = fmaxf(m, tv);
                }
                m = fmaxf(m, __shfl_xor(m, 1));
                m = fmaxf(m, __shfl_xor(m, 2));
                m = fmaxf(m, __shfl_xor(m, 4));
                m = fmaxf(m, __shfl_xor(m, 8));
                float inv = (m > 0.f) ? 255.f / m : 0.f;
                if (row < N) {
                    uint32 b0 = 0, b1 = 0;
                    #pragma unroll
                    for (int tl = 0; tl < 4; tl++)
                        b0 |= ((uint32)fmaf(v[tl], inv, 0.5f)) << (8 * tl);
                    #pragma unroll
                    for (int tl = 4; tl < 8; tl++)
                        b1 |= ((uint32)fmaf(v[tl], inv, 0.5f)) << (8 * (tl - 4));
                    ((uint2*)(Hq + (size_t)row * 128))[colSub] = make_uint2(b0, b1);
                    if (colSub == 0) scale[row] = m * (1.f / 255.f);
                }
            }
        };
        quant_rows(acc0, rowBase + rowOff);
        quant_rows(acc1, rowBase + rowOff + 16);
    } else {
        // stage block's 128x128 h2 tile in LDS (bf16); fused global-add-pool
        int blockBase = blockIdx.x * 128;
        #pragma unroll
        for (int tl = 0; tl < 8; tl++) {
            int col = tl * 16 + colSub;
            float bv = bias[col];
            #pragma unroll
            for (int r = 0; r < 4; r++) {
                int lrA = wave * 32 + rowOff + r;
                int lrB = lrA + 16;
                Hl[lrA * 128 + col] = packbf1(fmaxf(acc0[tl][r] + bv, 0.f));
                Hl[lrB * 128 + col] = packbf1(fmaxf(acc1[tl][r] + bv, 0.f));
            }
        }
        __syncthreads();
        if (t < 128) {
            int limit = N - blockBase; if (limit > 128) limit = 128;
            float s = 0.f;
            int gid = batch[blockBase];
            for (int r = 0; r < limit; r++) {
                int bg = batch[blockBase + r];
                if (bg != gid) {
                    atomicAdd(&g[gid * HID + t], s);
                    s = 0.f;
                    gid = bg;
                }
                s += b1f(Hl[r * 128 + t]);
            }
            atomicAdd(&g[gid * HID + t], s);
        }
    }
}

// ---------------------------------------------------------------- MLP (reads pre-pooled g)
__global__ __launch_bounds__(128) void mlp_kernel(const float* __restrict__ g,
                                                  const float* __restrict__ mW0, const float* __restrict__ mb0,
                                                  const float* __restrict__ mW1, const float* __restrict__ mb1,
                                                  const float* __restrict__ mW2, const float* __restrict__ mb2,
                                                  float* __restrict__ out) {
    int b = blockIdx.x;
    int j = threadIdx.x;
    __shared__ float l0[HID];
    __shared__ float l1[HID];
    l0[j] = g[b * HID + j];
    __syncthreads();

    {
        float a0 = mb0[j], a1 = 0.f, a2 = 0.f, a3 = 0.f;
        #pragma unroll 4
        for (int k = 0; k < HID; k += 4) {
            a0 = fmaf(l0[k + 0], mW0[(k + 0) * HID + j], a0);
            a1 = fmaf(l0[k + 1], mW0[(k + 1) * HID + j], a1);
            a2 = fmaf(l0[k + 2], mW0[(k + 2) * HID + j], a2);
            a3 = fmaf(l0[k + 3], mW0[(k + 3) * HID + j], a3);
        }
        l1[j] = fmaxf((a0 + a1) + (a2 + a3), 0.f);
    }
    __syncthreads();

    float c;
    {
        float a0 = mb1[j], a1 = 0.f, a2 = 0.f, a3 = 0.f;
        #pragma unroll 4
        for (int k = 0; k < HID; k += 4) {
            a0 = fmaf(l1[k + 0], mW1[(k + 0) * HID + j], a0);
            a1 = fmaf(l1[k + 1], mW1[(k + 1) * HID + j], a1);
            a2 = fmaf(l1[k + 2], mW1[(k + 2) * HID + j], a2);
            a3 = fmaf(l1[k + 3], mW1[(k + 3) * HID + j], a3);
        }
        c = fmaxf((a0 + a1) + (a2 + a3), 0.f);
    }
    __syncthreads();
    l0[j] = c;
    __syncthreads();

    if (j < N_CLASSES) {
        float a0 = mb2[j], a1 = 0.f, a2 = 0.f, a3 = 0.f;
        #pragma unroll 4
        for (int k = 0; k < HID; k += 4) {
            a0 = fmaf(l0[k + 0], mW2[(k + 0) * N_CLASSES + j], a0);
            a1 = fmaf(l0[k + 1], mW2[(k + 1) * N_CLASSES + j], a1);
            a2 = fmaf(l0[k + 2], mW2[(k + 2) * N_CLASSES + j], a2);
            a3 = fmaf(l0[k + 3], mW2[(k + 3) * N_CLASSES + j], a3);
        }
        out[b * N_CLASSES + j] = (a0 + a1) + (a2 + a3);
    }
}

// ---------------------------------------------------------------- launch
extern "C" void kernel_launch(void* const* d_in, const int* in_sizes, int n_in,
                              void* d_out, int out_size, void* d_ws, size_t ws_size,
                              hipStream_t stream) {
    const float* x     = (const float*)d_in[0];
    const int*   ei    = (const int*)d_in[1];
    const int*   batch = (const int*)d_in[2];
    const float* W0  = (const float*)d_in[3];
    const float* b0  = (const float*)d_in[4];
    const float* W1  = (const float*)d_in[5];
    const float* b1  = (const float*)d_in[6];
    const float* W2  = (const float*)d_in[7];
    const float* b2  = (const float*)d_in[8];
    const float* mW0 = (const float*)d_in[9];
    const float* mb0 = (const float*)d_in[10];
    const float* mW1 = (const float*)d_in[11];
    const float* mb1 = (const float*)d_in[12];
    const float* mW2 = (const float*)d_in[13];
    const float* mb2 = (const float*)d_in[14];
    float* out = (float*)d_out;

    const int N = N_NODES, E = N_EDGES;
    const int* src = ei;
    const int* dst = ei + E;

    char* w = (char*)d_ws;
    auto alloc = [&](size_t bytes) -> void* {
        void* p = (void*)w;
        w += (bytes + 255) & ~(size_t)255;
        return p;
    };
    int2*   rowse    = (int2*)alloc((size_t)N * 8);
    uint32* ebuf     = (uint32*)alloc((size_t)E * 4);
    uint32* meta     = (uint32*)alloc((size_t)E * 4);
    int*    bcnt     = (int*)alloc((size_t)MCNT * 4);
    int*    incl     = (int*)alloc((size_t)MCNT * 4);
    int*    bsum_raw = (int*)alloc(256 * 4);
    float*  dinv     = (float*)alloc((size_t)N * 4);
    float*  g        = (float*)alloc((size_t)NUM_GRAPHS * HID * 4);
    float*  scale    = (float*)alloc((size_t)N * 4);
    unsigned char*  Hq  = (unsigned char*)alloc((size_t)N * 128);
    unsigned short* xb  = (unsigned short*)alloc((size_t)N * F_IN * 2);
    unsigned short* agg = (unsigned short*)alloc((size_t)N * HID * 2);
    unsigned short* W0t = (unsigned short*)alloc((size_t)128 * (64 + 8) * 2);
    unsigned short* W1t = (unsigned short*)alloc((size_t)128 * (128 + 8) * 2);
    unsigned short* W2t = (unsigned short*)alloc((size_t)128 * (128 + 8) * 2);

    const int SPB = (N + 3) / 4;                // 12500
    const int GB  = (N + 127) / 128;            // 391

    // ---- prep + bucket CSR build (no global atomics)
    prep_hist_kernel<<<PREPB + S1B, 256, 0, stream>>>((const float4*)x, (uint2*)xb,
                                                      W0, W0t, W1, W1t, W2, W2t, g,
                                                      dst, bcnt, E);
    scanA_kernel<<<SCB, 256, 0, stream>>>(bcnt, incl, bsum_raw, MCNT);
    bscatter_kernel<<<S1B, 256, 0, stream>>>(src, dst, incl, bsum_raw, ebuf, E);
    bfinal_kernel<<<NBUCK, 256, 0, stream>>>(ebuf, bcnt, incl, bsum_raw, rowse, dinv, meta, E, N);

    // ---- layer 0: agg = A@x (+ norm fill) ; h0 = relu(agg@W0 + b0) -> u8 + scale
    spmm64_kernel<<<SPB, 256, 0, stream>>>(rowse, meta, dinv, xb, agg, N);
    gemm_mfma_kernel<64, false><<<GB, 256, 0, stream>>>(agg, W0t, b0, Hq, scale, batch, g, N);

    // ---- layer 1: agg = A@h0 (u8 gather) ; h1 -> u8 + scale
    spmm128q_kernel<<<SPB, 256, 0, stream>>>(rowse, meta, dinv, Hq, scale, agg, N);
    gemm_mfma_kernel<128, false><<<GB, 256, 0, stream>>>(agg, W1t, b1, Hq, scale, batch, g, N);

    // ---- layer 2: agg = A@h1 (u8 gather) ; h2 GEMM with fused global-add-pool
    spmm128q_kernel<<<SPB, 256, 0, stream>>>(rowse, meta, dinv, Hq, scale, agg, N);
    gemm_mfma_kernel<128, true><<<GB, 256, 0, stream>>>(agg, W2t, b2, Hq, scale, batch, g, N);

    // ---- MLP on pooled g
    mlp_kernel<<<NUM_GRAPHS, 128, 0, stream>>>(g, mW0, mb0, mW1, mb1, mW2, mb2, out);
}

// Round 15
// 177.533 us; speedup vs baseline: 1.0898x; 1.0898x over previous
//
#include <hip/hip_runtime.h>
#include <hip/hip_bf16.h>
#include <stdint.h>

#define N_NODES   50000
#define N_EDGES   800000
#define F_IN      64
#define HID       128
#define N_CLASSES 10
#define NUM_GRAPHS 512

// bucket-sort CSR build parameters
#define NBUCK 128      // buckets over dst
#define BW    391      // bucket width: 391*128 = 50048 >= N
#define S1B   400      // blocks in bucket hist/scatter
#define CHUNK 2000     // edges per block (400*2000 = 800000)
#define MCNT  (NBUCK * S1B)   // 51200 counters
#define SCB   (MCNT / 256)    // 200 scanA blocks
#define PREPB 3125     // blocks for prep range (N*F_IN/4/256)
#define MAXB  8192     // LDS staging capacity per bucket (mean 6250)

typedef unsigned int uint32;
typedef __attribute__((ext_vector_type(8))) short bf16x8;
typedef __attribute__((ext_vector_type(4))) float f32x4;

// ---------------- bf16 helpers (storage bf16, math fp32) ----------------
__device__ __forceinline__ float bl(uint32 w) { return __uint_as_float(w << 16); }
__device__ __forceinline__ float bh(uint32 w) { return __uint_as_float(w & 0xffff0000u); }
__device__ __forceinline__ float b1f(unsigned short h) { return __uint_as_float((uint32)h << 16); }
__device__ __forceinline__ uint32 packbf(float a, float b) {   // RNE, (a=low, b=high)
    uint32 ua = __float_as_uint(a), ub = __float_as_uint(b);
    ua = (ua + 0x7fffu + ((ua >> 16) & 1u)) >> 16;
    ub = (ub + 0x7fffu + ((ub >> 16) & 1u)) >> 16;
    return ua | (ub << 16);
}
__device__ __forceinline__ unsigned short packbf1(float a) {
    uint32 ua = __float_as_uint(a);
    return (unsigned short)((ua + 0x7fffu + ((ua >> 16) & 1u)) >> 16);
}

// physical column permutation for u8 activation rows: lane-contiguous stores
// phys(c) = (c&15)*8 + (c>>4)

// ---------------------------------------------------------------- prep + bucket hist (fused, disjoint block ranges)
__global__ __launch_bounds__(256) void prep_hist_kernel(const float4* __restrict__ x, uint2* __restrict__ xb,
                                                        const float* __restrict__ W0, unsigned short* __restrict__ W0t,
                                                        const float* __restrict__ W1, unsigned short* __restrict__ W1t,
                                                        const float* __restrict__ W2, unsigned short* __restrict__ W2t,
                                                        float* __restrict__ g,
                                                        const int* __restrict__ dst, int* __restrict__ bcnt, int E) {
    __shared__ int cnt[NBUCK];
    int blk = blockIdx.x;
    int t = threadIdx.x;
    if (blk < PREPB) {
        int i = blk * 256 + t;
        if (i < N_NODES * F_IN / 4) {
            float4 v = x[i];
            xb[i] = make_uint2(packbf(v.x, v.y), packbf(v.z, v.w));
        }
        if (i < NUM_GRAPHS * HID) g[i] = 0.f;
        if (i < 64 * 128) {
            int k = i >> 7, j = i & 127;
            W0t[j * (64 + 8) + k] = packbf1(W0[i]);   // natural rows (agg0 is bf16 natural)
        }
        int i2 = i - 64 * 128;
        if (i2 >= 0 && i2 < 128 * 128) {
            int k = i2 >> 7, j = i2 & 127;
            int kp = (k & 15) * 8 + (k >> 4);          // permuted rows (agg1/agg2 are physical order)
            W1t[j * (128 + 8) + kp] = packbf1(W1[i2]);
            W2t[j * (128 + 8) + kp] = packbf1(W2[i2]);
        }
    } else {
        int b2 = blk - PREPB;                  // 0..S1B-1
        if (t < NBUCK) cnt[t] = 0;
        __syncthreads();
        int base = b2 * CHUNK;
        for (int i = t; i < CHUNK; i += 256) {
            int e = base + i;
            if (e < E) atomicAdd(&cnt[(uint32)dst[e] / BW], 1);
        }
        __syncthreads();
        if (t < NBUCK) bcnt[t * S1B + b2] = cnt[t];   // bucket-major layout
    }
}

// ------------------------------------------------- scanA (per-256 inclusive + raw block sums)
__global__ __launch_bounds__(256) void scanA_kernel(const int* __restrict__ in,
                                                    int* __restrict__ incl,
                                                    int* __restrict__ bsum_raw, int M) {
    __shared__ int s[256];
    int t = threadIdx.x;
    int i = blockIdx.x * 256 + t;
    int v = (i < M) ? in[i] : 0;
    s[t] = v;
    __syncthreads();
    #pragma unroll
    for (int d = 1; d < 256; d <<= 1) {
        int a = (t >= d) ? s[t - d] : 0;
        __syncthreads();
        s[t] += a;
        __syncthreads();
    }
    if (i < M) incl[i] = s[t];
    if (t == 255) bsum_raw[blockIdx.x] = s[255];
}

// local exclusive scan of the 200 raw block sums (device helper)
__device__ __forceinline__ void local_top_scan(const int* __restrict__ bsum_raw, int* exs, int t) {
    int bv = (t < SCB) ? bsum_raw[t] : 0;
    exs[t] = bv;
    __syncthreads();
    #pragma unroll
    for (int d = 1; d < 256; d <<= 1) {
        int a = (t >= d) ? exs[t - d] : 0;
        __syncthreads();
        exs[t] += a;
        __syncthreads();
    }
    int iv = exs[t];
    __syncthreads();
    exs[t] = iv - bv;      // exclusive
    __syncthreads();
}

// S2: scatter edges into bucket-grouped ebuf (LDS cursors; 4B packed src|dst<<16)
__global__ __launch_bounds__(256) void bscatter_kernel(const int* __restrict__ src,
                                                       const int* __restrict__ dst,
                                                       const int* __restrict__ incl,
                                                       const int* __restrict__ bsum_raw,
                                                       uint32* __restrict__ ebuf, int E) {
    __shared__ int exs[256];
    __shared__ int cnt[NBUCK];
    __shared__ int cur[NBUCK];
    int t = threadIdx.x, blk = blockIdx.x;

    local_top_scan(bsum_raw, exs, t);

    if (t < NBUCK) cnt[t] = 0;
    __syncthreads();
    int base = blk * CHUNK;
    for (int i = t; i < CHUNK; i += 256) {
        int e = base + i;
        if (e < E) atomicAdd(&cnt[(uint32)dst[e] / BW], 1);
    }
    __syncthreads();
    if (t < NBUCK) {
        int idx = t * S1B + blk;
        cur[t] = exs[idx >> 8] + incl[idx] - cnt[t];   // global exclusive base
    }
    __syncthreads();
    for (int i = t; i < CHUNK; i += 256) {
        int e = base + i;
        if (e < E) {
            int d = dst[e];
            int slot = atomicAdd(&cur[(uint32)d / BW], 1);
            ebuf[slot] = (uint32)src[e] | ((uint32)d << 16);
        }
    }
}

// S3: per-bucket CSR finalize
__global__ __launch_bounds__(256) void bfinal_kernel(const uint32* __restrict__ ebuf,
                                                     const int* __restrict__ bcnt,
                                                     const int* __restrict__ incl,
                                                     const int* __restrict__ bsum_raw,
                                                     int2* __restrict__ rowse,
                                                     float* __restrict__ dinv,
                                                     uint32* __restrict__ meta, int E, int N) {
    __shared__ int exs[256];
    __shared__ int cnt[392];
    __shared__ int startv[400];
    __shared__ int segt[16];
    __shared__ uint32 smeta[MAXB];
    int t = threadIdx.x, b = blockIdx.x;

    local_top_scan(bsum_raw, exs, t);

    int bs, be;
    {
        int idx = b * S1B;
        bs = exs[idx >> 8] + incl[idx] - bcnt[idx];
        if (b + 1 >= NBUCK) be = E;
        else {
            int idx1 = (b + 1) * S1B;
            be = exs[idx1 >> 8] + incl[idx1] - bcnt[idx1];
        }
    }
    int sz = be - bs;

    for (int i = t; i < 392; i += 256) cnt[i] = 0;
    __syncthreads();
    for (int i = bs + t; i < be; i += 256) {
        uint32 d = ebuf[i] >> 16;
        atomicAdd(&cnt[d - b * BW], 1);
    }
    __syncthreads();

    if (t < 16) {
        int run = 0;
        #pragma unroll
        for (int k = 0; k < 25; k++) {
            int idx = t * 25 + k;
            int c = (idx < 391) ? cnt[idx] : 0;
            startv[idx] = run;
            run += c;
        }
        segt[t] = run;
    }
    __syncthreads();
    if (t == 0) {
        int run = 0;
        #pragma unroll
        for (int j = 0; j < 16; j++) { int s = segt[j]; segt[j] = run; run += s; }
    }
    __syncthreads();
    for (int l = t; l < 391; l += 256) startv[l] += segt[l / 25];
    __syncthreads();

    int locN = N - b * BW; if (locN > BW) locN = BW;
    for (int l = t; l < locN; l += 256) {
        int gn = b * BW + l;
        int st = bs + startv[l];
        rowse[gn] = make_int2(st, st + cnt[l]);
        dinv[gn] = rsqrtf((float)(cnt[l] + 1));
    }
    __syncthreads();

    if (sz <= MAXB) {
        for (int i = bs + t; i < be; i += 256) {
            uint32 v = ebuf[i];
            int slot = atomicAdd(&startv[(v >> 16) - b * BW], 1);
            smeta[slot] = v;
        }
        __syncthreads();
        for (int i = t; i < sz; i += 256) meta[bs + i] = smeta[i];
    } else {
        for (int i = bs + t; i < be; i += 256) {
            uint32 v = ebuf[i];
            int slot = atomicAdd(&startv[(v >> 16) - b * BW], 1);
            meta[bs + slot] = v;
        }
    }
}

// ---------------------------------------------------------------- SpMM 64-wide bf16 + norm fill
__global__ __launch_bounds__(256) void spmm64_kernel(const int2* __restrict__ rowse,
                                                     uint32* __restrict__ meta,
                                                     const float* __restrict__ dinv,
                                                     const unsigned short* __restrict__ Hin,
                                                     unsigned short* __restrict__ Hout, int N) {
    int wave = threadIdx.x >> 6;
    int lane = threadIdx.x & 63;
    int node = blockIdx.x * 4 + wave;
    if (node >= N) return;
    int oct = lane >> 3;
    int sub = lane & 7;

    const uint4* Hv = (const uint4*)Hin;     // row = 8 chunks of 8 bf16
    float di = dinv[node];
    float sn = di * di;

    float acc[8];
    if (oct == 0) {
        uint4 s = Hv[(size_t)node * 8 + sub];
        acc[0] = sn * bl(s.x); acc[1] = sn * bh(s.x);
        acc[2] = sn * bl(s.y); acc[3] = sn * bh(s.y);
        acc[4] = sn * bl(s.z); acc[5] = sn * bh(s.z);
        acc[6] = sn * bl(s.w); acc[7] = sn * bh(s.w);
    } else {
        #pragma unroll
        for (int v = 0; v < 8; v++) acc[v] = 0.f;
    }

    int2 se = rowse[node];
    int e0 = se.x, e1 = se.y;
    for (int e = e0; e < e1; e += 16) {
        int i0 = e + oct;
        int i1 = e + 8 + oct;
        bool v0 = i0 < e1, v1 = i1 < e1;
        uint32 m0 = v0 ? meta[i0] : 0u;
        uint32 m1 = v1 ? meta[i1] : 0u;
        uint32 s0 = m0 & 0xffffu, s1 = m1 & 0xffffu;
        float n0 = v0 ? di * dinv[s0] : 0.f;
        float n1 = v1 ? di * dinv[s1] : 0.f;
        if (sub == 0) {   // one lane per edge writes the normed meta back
            if (v0) meta[i0] = s0 | ((uint32)packbf1(n0) << 16);
            if (v1) meta[i1] = s1 | ((uint32)packbf1(n1) << 16);
        }
        uint4 r0 = Hv[(size_t)s0 * 8 + sub];
        uint4 r1 = Hv[(size_t)s1 * 8 + sub];
        acc[0] = fmaf(n0, bl(r0.x), acc[0]); acc[1] = fmaf(n0, bh(r0.x), acc[1]);
        acc[2] = fmaf(n0, bl(r0.y), acc[2]); acc[3] = fmaf(n0, bh(r0.y), acc[3]);
        acc[4] = fmaf(n0, bl(r0.z), acc[4]); acc[5] = fmaf(n0, bh(r0.z), acc[5]);
        acc[6] = fmaf(n0, bl(r0.w), acc[6]); acc[7] = fmaf(n0, bh(r0.w), acc[7]);
        acc[0] = fmaf(n1, bl(r1.x), acc[0]); acc[1] = fmaf(n1, bh(r1.x), acc[1]);
        acc[2] = fmaf(n1, bl(r1.y), acc[2]); acc[3] = fmaf(n1, bh(r1.y), acc[3]);
        acc[4] = fmaf(n1, bl(r1.z), acc[4]); acc[5] = fmaf(n1, bh(r1.z), acc[5]);
        acc[6] = fmaf(n1, bl(r1.w), acc[6]); acc[7] = fmaf(n1, bh(r1.w), acc[7]);
    }

    #pragma unroll
    for (int v = 0; v < 8; v++) {
        acc[v] += __shfl_xor(acc[v], 8);
        acc[v] += __shfl_xor(acc[v], 16);
        acc[v] += __shfl_xor(acc[v], 32);
    }

    if (oct == 0) {
        uint4 o;
        o.x = packbf(acc[0], acc[1]);
        o.y = packbf(acc[2], acc[3]);
        o.z = packbf(acc[4], acc[5]);
        o.w = packbf(acc[6], acc[7]);
        ((uint4*)Hout)[(size_t)node * 8 + sub] = o;
    }
}

// ---------------------------------------------------------------- SpMM 128-wide over u8-quantized rows
// Hq rows: 128 u8 (physical col order) + per-row f32 scale. Output: bf16 agg rows (physical order).
__device__ __forceinline__ void fma16_u8(uint4 u, float ns, float* acc) {
    #pragma unroll
    for (int w = 0; w < 4; w++) {
        uint32 xv = (&u.x)[w];
        acc[w * 4 + 0] = fmaf(ns, (float)(xv & 255u),         acc[w * 4 + 0]);
        acc[w * 4 + 1] = fmaf(ns, (float)((xv >> 8) & 255u),  acc[w * 4 + 1]);
        acc[w * 4 + 2] = fmaf(ns, (float)((xv >> 16) & 255u), acc[w * 4 + 2]);
        acc[w * 4 + 3] = fmaf(ns, (float)(xv >> 24),          acc[w * 4 + 3]);
    }
}

__global__ __launch_bounds__(256) void spmm128q_kernel(const int2* __restrict__ rowse,
                                                       const uint32* __restrict__ meta,
                                                       const float* __restrict__ dinv,
                                                       const unsigned char* __restrict__ Hq,
                                                       const float* __restrict__ scale,
                                                       unsigned short* __restrict__ Hout, int N) {
    int wave = threadIdx.x >> 6;
    int lane = threadIdx.x & 63;
    int node = blockIdx.x * 4 + wave;
    if (node >= N) return;
    int oct = lane >> 3;     // edge slot 0..7
    int sub = lane & 7;      // 16B chunk 0..7

    const uint4* Hv = (const uint4*)Hq;      // row = 8 uint4 (128 u8)
    float di = dinv[node];
    float sn = di * di;

    float acc[16];
    #pragma unroll
    for (int v = 0; v < 16; v++) acc[v] = 0.f;
    if (oct == 0) {
        uint4 u = Hv[(size_t)node * 8 + sub];
        float ss = sn * scale[node];
        fma16_u8(u, ss, acc);
    }

    int2 se = rowse[node];
    int e0 = se.x, e1 = se.y;
    for (int e = e0; e < e1; e += 16) {
        int i0 = e + oct;
        int i1 = e + 8 + oct;
        uint32 m0 = (i0 < e1) ? meta[i0] : 0u;   // norm=0 -> no-op
        uint32 m1 = (i1 < e1) ? meta[i1] : 0u;
        uint32 s0 = m0 & 0xffffu, s1 = m1 & 0xffffu;
        float ns0 = bh(m0) * scale[s0];
        float ns1 = bh(m1) * scale[s1];
        uint4 u0 = Hv[(size_t)s0 * 8 + sub];
        uint4 u1 = Hv[(size_t)s1 * 8 + sub];
        fma16_u8(u0, ns0, acc);
        fma16_u8(u1, ns1, acc);
    }

    #pragma unroll
    for (int v = 0; v < 16; v++) {
        acc[v] += __shfl_xor(acc[v], 8);
        acc[v] += __shfl_xor(acc[v], 16);
        acc[v] += __shfl_xor(acc[v], 32);
    }

    if (oct == 0) {
        uint32 o[8];
        #pragma unroll
        for (int i = 0; i < 8; i++) o[i] = packbf(acc[2 * i], acc[2 * i + 1]);
        uint4* dst = (uint4*)(Hout + (size_t)node * 128) + sub * 2;
        dst[0] = make_uint4(o[0], o[1], o[2], o[3]);
        dst[1] = make_uint4(o[4], o[5], o[6], o[7]);
    }
}

// ---------------------------------------------------------------- MFMA GEMM (bf16 A/W)
// POOL=false: epilogue quantizes rows to u8 (physical col order) + per-row scale.
// POOL=true : epilogue stages bf16 tile in LDS and does fused global-add-pool.
template <int K, bool POOL>
__global__ __launch_bounds__(256) void gemm_mfma_kernel(const unsigned short* __restrict__ A,
                                                        const unsigned short* __restrict__ Wt,
                                                        const float* __restrict__ bias,
                                                        unsigned char* __restrict__ Hq,
                                                        float* __restrict__ scale,
                                                        const int* __restrict__ batch,
                                                        float* __restrict__ g,
                                                        int N) {
    constexpr int KP = K + 8;
    __shared__ unsigned short Wl[128 * KP];
    __shared__ unsigned short Hl[POOL ? 128 * 128 : 1];

    int t = threadIdx.x;
    constexpr int TOT = 128 * KP * 2 / 16;     // uint4 chunks
    #pragma unroll
    for (int i = 0; i < (TOT + 255) / 256; i++) {
        int idx = i * 256 + t;
        if (idx < TOT) ((uint4*)Wl)[idx] = ((const uint4*)Wt)[idx];
    }
    __syncthreads();

    int wave = t >> 6;
    int lane = t & 63;
    int rowBase = blockIdx.x * 128 + wave * 32;
    int r0 = rowBase + (lane & 15);
    int r1 = r0 + 16;
    if (r0 >= N) r0 = N - 1;                   // clamp (stores predicated)
    if (r1 >= N) r1 = N - 1;
    int kchunk = lane >> 4;                    // 0..3
    int colSub = lane & 15;

    f32x4 acc0[8], acc1[8];
    #pragma unroll
    for (int i = 0; i < 8; i++) { acc0[i] = (f32x4)0.0f; acc1[i] = (f32x4)0.0f; }

    #pragma unroll
    for (int s = 0; s < K / 32; s++) {
        bf16x8 a0 = *(const bf16x8*)(A + (size_t)r0 * K + s * 32 + kchunk * 8);
        bf16x8 a1 = *(const bf16x8*)(A + (size_t)r1 * K + s * 32 + kchunk * 8);
        #pragma unroll
        for (int tl = 0; tl < 8; tl++) {
            bf16x8 b = *(const bf16x8*)(Wl + (tl * 16 + colSub) * KP + s * 32 + kchunk * 8);
            acc0[tl] = __builtin_amdgcn_mfma_f32_16x16x32_bf16(a0, b, acc0[tl], 0, 0, 0);
            acc1[tl] = __builtin_amdgcn_mfma_f32_16x16x32_bf16(a1, b, acc1[tl], 0, 0, 0);
        }
    }

    int rowOff = (lane >> 4) * 4;
    if (!POOL) {
        // quantize each output row to u8 with per-row scale; lane stores 8 contiguous bytes
        auto quant_rows = [&](f32x4 (&ac)[8], int rbase) {
            #pragma unroll
            for (int r = 0; r < 4; r++) {
                int row = rbase + r;
                float v[8];
                float m = 0.f;
                #pragma unroll
                for (int tl = 0; tl < 8; tl++) {
                    float tv = fmaxf(ac[tl][r] + bias[tl * 16 + colSub], 0.f);
                    v[tl] = tv;
                    m = fmaxf(m, tv);
                }
                m = fmaxf(m, __shfl_xor(m, 1));
                m = fmaxf(m, __shfl_xor(m, 2));
                m = fmaxf(m, __shfl_xor(m, 4));
                m = fmaxf(m, __shfl_xor(m, 8));
                float inv = (m > 0.f) ? 255.f / m : 0.f;
                if (row < N) {
                    uint32 b0 = 0, b1 = 0;
                    #pragma unroll
                    for (int tl = 0; tl < 4; tl++)
                        b0 |= ((uint32)fmaf(v[tl], inv, 0.5f)) << (8 * tl);
                    #pragma unroll
                    for (int tl = 4; tl < 8; tl++)
                        b1 |= ((uint32)fmaf(v[tl], inv, 0.5f)) << (8 * (tl - 4));
                    ((uint2*)(Hq + (size_t)row * 128))[colSub] = make_uint2(b0, b1);
                    if (colSub == 0) scale[row] = m * (1.f / 255.f);
                }
            }
        };
        quant_rows(acc0, rowBase + rowOff);
        quant_rows(acc1, rowBase + rowOff + 16);
    } else {
        // stage block's 128x128 h2 tile in LDS (bf16); fused global-add-pool
        int blockBase = blockIdx.x * 128;
        #pragma unroll
        for (int tl = 0; tl < 8; tl++) {
            int col = tl * 16 + colSub;
            float bv = bias[col];
            #pragma unroll
            for (int r = 0; r < 4; r++) {
                int lrA = wave * 32 + rowOff + r;
                int lrB = lrA + 16;
                Hl[lrA * 128 + col] = packbf1(fmaxf(acc0[tl][r] + bv, 0.f));
                Hl[lrB * 128 + col] = packbf1(fmaxf(acc1[tl][r] + bv, 0.f));
            }
        }
        __syncthreads();
        if (t < 128) {
            int limit = N - blockBase; if (limit > 128) limit = 128;
            float s = 0.f;
            int gid = batch[blockBase];
            for (int r = 0; r < limit; r++) {
                int bg = batch[blockBase + r];
                if (bg != gid) {
                    atomicAdd(&g[gid * HID + t], s);
                    s = 0.f;
                    gid = bg;
                }
                s += b1f(Hl[r * 128 + t]);
            }
            atomicAdd(&g[gid * HID + t], s);
        }
    }
}

// ---------------------------------------------------------------- MLP (reads pre-pooled g)
__global__ __launch_bounds__(128) void mlp_kernel(const float* __restrict__ g,
                                                  const float* __restrict__ mW0, const float* __restrict__ mb0,
                                                  const float* __restrict__ mW1, const float* __restrict__ mb1,
                                                  const float* __restrict__ mW2, const float* __restrict__ mb2,
                                                  float* __restrict__ out) {
    int b = blockIdx.x;
    int j = threadIdx.x;
    __shared__ float l0[HID];
    __shared__ float l1[HID];
    l0[j] = g[b * HID + j];
    __syncthreads();

    {
        float a0 = mb0[j], a1 = 0.f, a2 = 0.f, a3 = 0.f;
        #pragma unroll 4
        for (int k = 0; k < HID; k += 4) {
            a0 = fmaf(l0[k + 0], mW0[(k + 0) * HID + j], a0);
            a1 = fmaf(l0[k + 1], mW0[(k + 1) * HID + j], a1);
            a2 = fmaf(l0[k + 2], mW0[(k + 2) * HID + j], a2);
            a3 = fmaf(l0[k + 3], mW0[(k + 3) * HID + j], a3);
        }
        l1[j] = fmaxf((a0 + a1) + (a2 + a3), 0.f);
    }
    __syncthreads();

    float c;
    {
        float a0 = mb1[j], a1 = 0.f, a2 = 0.f, a3 = 0.f;
        #pragma unroll 4
        for (int k = 0; k < HID; k += 4) {
            a0 = fmaf(l1[k + 0], mW1[(k + 0) * HID + j], a0);
            a1 = fmaf(l1[k + 1], mW1[(k + 1) * HID + j], a1);
            a2 = fmaf(l1[k + 2], mW1[(k + 2) * HID + j], a2);
            a3 = fmaf(l1[k + 3], mW1[(k + 3) * HID + j], a3);
        }
        c = fmaxf((a0 + a1) + (a2 + a3), 0.f);
    }
    __syncthreads();
    l0[j] = c;
    __syncthreads();

    if (j < N_CLASSES) {
        float a0 = mb2[j], a1 = 0.f, a2 = 0.f, a3 = 0.f;
        #pragma unroll 4
        for (int k = 0; k < HID; k += 4) {
            a0 = fmaf(l0[k + 0], mW2[(k + 0) * N_CLASSES + j], a0);
            a1 = fmaf(l0[k + 1], mW2[(k + 1) * N_CLASSES + j], a1);
            a2 = fmaf(l0[k + 2], mW2[(k + 2) * N_CLASSES + j], a2);
            a3 = fmaf(l0[k + 3], mW2[(k + 3) * N_CLASSES + j], a3);
        }
        out[b * N_CLASSES + j] = (a0 + a1) + (a2 + a3);
    }
}

// ---------------------------------------------------------------- launch
extern "C" void kernel_launch(void* const* d_in, const int* in_sizes, int n_in,
                              void* d_out, int out_size, void* d_ws, size_t ws_size,
                              hipStream_t stream) {
    const float* x     = (const float*)d_in[0];
    const int*   ei    = (const int*)d_in[1];
    const int*   batch = (const int*)d_in[2];
    const float* W0  = (const float*)d_in[3];
    const float* b0  = (const float*)d_in[4];
    const float* W1  = (const float*)d_in[5];
    const float* b1  = (const float*)d_in[6];
    const float* W2  = (const float*)d_in[7];
    const float* b2  = (const float*)d_in[8];
    const float* mW0 = (const float*)d_in[9];
    const float* mb0 = (const float*)d_in[10];
    const float* mW1 = (const float*)d_in[11];
    const float* mb1 = (const float*)d_in[12];
    const float* mW2 = (const float*)d_in[13];
    const float* mb2 = (const float*)d_in[14];
    float* out = (float*)d_out;

    const int N = N_NODES, E = N_EDGES;
    const int* src = ei;
    const int* dst = ei + E;

    char* w = (char*)d_ws;
    auto alloc = [&](size_t bytes) -> void* {
        void* p = (void*)w;
        w += (bytes + 255) & ~(size_t)255;
        return p;
    };
    int2*   rowse    = (int2*)alloc((size_t)N * 8);
    uint32* ebuf     = (uint32*)alloc((size_t)E * 4);
    uint32* meta     = (uint32*)alloc((size_t)E * 4);
    int*    bcnt     = (int*)alloc((size_t)MCNT * 4);
    int*    incl     = (int*)alloc((size_t)MCNT * 4);
    int*    bsum_raw = (int*)alloc(256 * 4);
    float*  dinv     = (float*)alloc((size_t)N * 4);
    float*  g        = (float*)alloc((size_t)NUM_GRAPHS * HID * 4);
    float*  scale    = (float*)alloc((size_t)N * 4);
    unsigned char*  Hq  = (unsigned char*)alloc((size_t)N * 128);
    unsigned short* xb  = (unsigned short*)alloc((size_t)N * F_IN * 2);
    unsigned short* agg = (unsigned short*)alloc((size_t)N * HID * 2);
    unsigned short* W0t = (unsigned short*)alloc((size_t)128 * (64 + 8) * 2);
    unsigned short* W1t = (unsigned short*)alloc((size_t)128 * (128 + 8) * 2);
    unsigned short* W2t = (unsigned short*)alloc((size_t)128 * (128 + 8) * 2);

    const int SPB = (N + 3) / 4;                // 12500
    const int GB  = (N + 127) / 128;            // 391

    // ---- prep + bucket CSR build (no global atomics)
    prep_hist_kernel<<<PREPB + S1B, 256, 0, stream>>>((const float4*)x, (uint2*)xb,
                                                      W0, W0t, W1, W1t, W2, W2t, g,
                                                      dst, bcnt, E);
    scanA_kernel<<<SCB, 256, 0, stream>>>(bcnt, incl, bsum_raw, MCNT);
    bscatter_kernel<<<S1B, 256, 0, stream>>>(src, dst, incl, bsum_raw, ebuf, E);
    bfinal_kernel<<<NBUCK, 256, 0, stream>>>(ebuf, bcnt, incl, bsum_raw, rowse, dinv, meta, E, N);

    // ---- layer 0: agg = A@x (+ norm fill) ; h0 = relu(agg@W0 + b0) -> u8 + scale
    spmm64_kernel<<<SPB, 256, 0, stream>>>(rowse, meta, dinv, xb, agg, N);
    gemm_mfma_kernel<64, false><<<GB, 256, 0, stream>>>(agg, W0t, b0, Hq, scale, batch, g, N);

    // ---- layer 1: agg = A@h0 (u8 gather) ; h1 -> u8 + scale
    spmm128q_kernel<<<SPB, 256, 0, stream>>>(rowse, meta, dinv, Hq, scale, agg, N);
    gemm_mfma_kernel<128, false><<<GB, 256, 0, stream>>>(agg, W1t, b1, Hq, scale, batch, g, N);

    // ---- layer 2: agg = A@h1 (u8 gather) ; h2 GEMM with fused global-add-pool
    spmm128q_kernel<<<SPB, 256, 0, stream>>>(rowse, meta, dinv, Hq, scale, agg, N);
    gemm_mfma_kernel<128, true><<<GB, 256, 0, stream>>>(agg, W2t, b2, Hq, scale, batch, g, N);

    // ---- MLP on pooled g
    mlp_kernel<<<NUM_GRAPHS, 128, 0, stream>>>(g, mW0, mb0, mW1, mb1, mW2, mb2, out);
}